// Round 8
// baseline (1690.523 us; speedup 1.0000x reference)
//
#include <hip/hip_runtime.h>
#include <hip/hip_bf16.h>
#include <math.h>

namespace {

constexpr int kH     = 512;
constexpr int kL     = 1024;
constexpr int kB     = 64;
constexpr int kHalf  = 256;
constexpr int kV     = 32000;
constexpr int kTok   = kB * kL;     // 65536

using f32x4 = __attribute__((ext_vector_type(4))) float;
using f16x8 = __attribute__((ext_vector_type(8))) _Float16;

__device__ inline void fsplit(float v, _Float16& h, _Float16& l) {
  h = (_Float16)v;
  l = (_Float16)(v - (float)h);
}

// async global->LDS, 16B per lane; dest = wave-uniform base + lane*16
#define GLD16(dst, src) \
  __builtin_amdgcn_global_load_lds( \
      (const __attribute__((address_space(1))) void*)(src), \
      (__attribute__((address_space(3))) void*)(dst), 16, 0, 0)

// ---------------- positional weights
__global__ void pos_kernel(const float* __restrict__ pos_emb,
                           const float* __restrict__ pos_w,
                           const float* __restrict__ pos_b,
                           float* __restrict__ wts)
{
  int t = blockIdx.x * blockDim.x + threadIdx.x;
  if (t >= kL) return;
  float z = pos_b[0];
#pragma unroll
  for (int p = 0; p < 16; ++p) z += pos_emb[t * 16 + p] * pos_w[p];
  wts[t] = 1.f / (1.f + expf(-z));
}

// ---------------- transpose + hi/lo fp16 split: W[K][N] fp32 -> Th/Tl[N][K]
__global__ __launch_bounds__(256) void transpose_split(
    const float* __restrict__ W, _Float16* __restrict__ Th,
    _Float16* __restrict__ Tl, int N, int kshift)
{
  const int idx = blockIdx.x * 256 + threadIdx.x;
  const int K = 1 << kshift;
  const int k = idx & (K - 1);
  const int n = idx >> kshift;
  const float w = W[(size_t)k * N + n];
  const _Float16 h = (_Float16)w;
  Th[idx] = h;
  Tl[idx] = (_Float16)(w - (float)h);
}

// ---------------- split-fp16 MFMA GEMM: C[M,N] = A[M,K] @ (Bh+Bl)[N,K]^T
// v2: operand staging via global_load_lds width=16 (r7: −30us vs reg-stage).
union HgemmLds {
  struct { _Float16 A[2][128][40]; _Float16 Bh[128][32]; _Float16 Bl[128][32]; } e0; // 36864 B
  struct { _Float16 G[4][128][32]; } e1;                                             // 32768 B
};

template <int EPI>
__global__ __launch_bounds__(256) void hgemm(
    const int* __restrict__ seq, const float* __restrict__ embed,
    const _Float16* __restrict__ Ah, const _Float16* __restrict__ Al,
    const _Float16* __restrict__ Bh, const _Float16* __restrict__ Bl,
    const float* __restrict__ bias, const float* __restrict__ bias2,
    float* __restrict__ Xout, _Float16* __restrict__ Oh, _Float16* __restrict__ Ol,
    float* __restrict__ ks, float* __restrict__ ke,
    int K, int N, int tok0c)
{
  __shared__ HgemmLds u;
  const int tid  = threadIdx.x;
  const int lane = tid & 63;
  const int wv   = tid >> 6;
  const int wm   = (wv >> 1) * 64;
  const int wn   = (wv & 1) * 64;
  const int bm0  = blockIdx.y * 128;
  const int bn0  = blockIdx.x * 128;

  f32x4 acc[4][4];
#pragma unroll
  for (int i = 0; i < 4; ++i)
#pragma unroll
    for (int j = 0; j < 4; ++j) acc[i][j] = {0.f, 0.f, 0.f, 0.f};

  // gload lane geometry: lane l covers row (chunk + l>>2), bytes (l&3)*16
  const int glr = lane >> 2;
  const int glc = (lane & 3) * 8;          // halves
  const _Float16* gB0h = Bh + (size_t)(bn0 + wv * 32 + glr) * K + glc;
  const _Float16* gB0l = Bl + (size_t)(bn0 + wv * 32 + glr) * K + glc;
  const _Float16* gA0h = nullptr;
  const _Float16* gA0l = nullptr;
  const float*    gAe  = nullptr;
  const int sr = tid >> 1;                 // EPI0 A staging row
  const int sc = (tid & 1) << 4;
  if constexpr (EPI == 0) {
    const int tokrow = seq[tok0c + bm0 + sr];
    gAe = embed + (size_t)tokrow * kH + sc;
  } else {
    gA0h = Ah + (size_t)(bm0 + wv * 32 + glr) * K + glc;
    gA0l = Al + (size_t)(bm0 + wv * 32 + glr) * K + glc;
  }

  const int lrow = lane & 15;
  const int lk   = (lane >> 4) * 8;

  // wave-uniform LDS dest bases (halves)
  _Float16* dBh; _Float16* dBl;
  _Float16* dAh = nullptr; _Float16* dAl = nullptr;
  if constexpr (EPI == 0) {
    dBh = &u.e0.Bh[0][0]; dBl = &u.e0.Bl[0][0];
  } else {
    dAh = &u.e1.G[0][0][0]; dAl = &u.e1.G[1][0][0];
    dBh = &u.e1.G[2][0][0]; dBl = &u.e1.G[3][0][0];
  }
  const int lo0 = (wv * 32) * 32;          // wave chunk 0 offset (halves)
  const int lo1 = (wv * 32 + 16) * 32;     // wave chunk 1

  for (int k0 = 0; k0 < K; k0 += 32) {
    if constexpr (EPI == 0) {
      // A loads issued before the barrier (overlap with prev MFMA phase)
      const float4 a0 = *(const float4*)(gAe + k0);
      const float4 a1 = *(const float4*)(gAe + k0 + 4);
      const float4 a2 = *(const float4*)(gAe + k0 + 8);
      const float4 a3 = *(const float4*)(gAe + k0 + 12);
      const float vv[16] = {a0.x,a0.y,a0.z,a0.w, a1.x,a1.y,a1.z,a1.w,
                            a2.x,a2.y,a2.z,a2.w, a3.x,a3.y,a3.z,a3.w};
      union { _Float16 h[16]; uint4 uu[2]; } ph, pl;
#pragma unroll
      for (int i = 0; i < 16; ++i) fsplit(vv[i], ph.h[i], pl.h[i]);
      __syncthreads();                     // prev LDS readers done
      GLD16(dBh + lo0, gB0h + k0);
      GLD16(dBh + lo1, gB0h + (size_t)16 * K + k0);
      GLD16(dBl + lo0, gB0l + k0);
      GLD16(dBl + lo1, gB0l + (size_t)16 * K + k0);
      *(uint4*)&u.e0.A[0][sr][sc]     = ph.uu[0];
      *(uint4*)&u.e0.A[0][sr][sc + 8] = ph.uu[1];
      *(uint4*)&u.e0.A[1][sr][sc]     = pl.uu[0];
      *(uint4*)&u.e0.A[1][sr][sc + 8] = pl.uu[1];
    } else {
      __syncthreads();                     // prev LDS readers done
      GLD16(dAh + lo0, gA0h + k0);
      GLD16(dAh + lo1, gA0h + (size_t)16 * K + k0);
      GLD16(dAl + lo0, gA0l + k0);
      GLD16(dAl + lo1, gA0l + (size_t)16 * K + k0);
      GLD16(dBh + lo0, gB0h + k0);
      GLD16(dBh + lo1, gB0h + (size_t)16 * K + k0);
      GLD16(dBl + lo0, gB0l + k0);
      GLD16(dBl + lo1, gB0l + (size_t)16 * K + k0);
    }
    __syncthreads();                       // drains vmcnt: tiles ready

    f16x8 fBh[4], fBl[4];
#pragma unroll
    for (int ni = 0; ni < 4; ++ni) {
      if constexpr (EPI == 0) {
        fBh[ni] = *(const f16x8*)&u.e0.Bh[wn + ni * 16 + lrow][lk];
        fBl[ni] = *(const f16x8*)&u.e0.Bl[wn + ni * 16 + lrow][lk];
      } else {
        fBh[ni] = *(const f16x8*)&u.e1.G[2][wn + ni * 16 + lrow][lk];
        fBl[ni] = *(const f16x8*)&u.e1.G[3][wn + ni * 16 + lrow][lk];
      }
    }
#pragma unroll
    for (int mi = 0; mi < 4; ++mi) {
      f16x8 ah, al;
      if constexpr (EPI == 0) {
        ah = *(const f16x8*)&u.e0.A[0][wm + mi * 16 + lrow][lk];
        al = *(const f16x8*)&u.e0.A[1][wm + mi * 16 + lrow][lk];
      } else {
        ah = *(const f16x8*)&u.e1.G[0][wm + mi * 16 + lrow][lk];
        al = *(const f16x8*)&u.e1.G[1][wm + mi * 16 + lrow][lk];
      }
#pragma unroll
      for (int ni = 0; ni < 4; ++ni) {
        acc[mi][ni] = __builtin_amdgcn_mfma_f32_16x16x32_f16(ah, fBh[ni], acc[mi][ni], 0, 0, 0);
        acc[mi][ni] = __builtin_amdgcn_mfma_f32_16x16x32_f16(ah, fBl[ni], acc[mi][ni], 0, 0, 0);
        acc[mi][ni] = __builtin_amdgcn_mfma_f32_16x16x32_f16(al, fBh[ni], acc[mi][ni], 0, 0, 0);
      }
    }
  }

  const int erow0 = (lane >> 4) * 4;
  if constexpr (EPI == 0) {
#pragma unroll
    for (int mi = 0; mi < 4; ++mi)
#pragma unroll
      for (int ni = 0; ni < 4; ++ni) {
        const int gn = bn0 + wn + ni * 16 + (lane & 15);
        const float bv = bias[gn];
#pragma unroll
        for (int r = 0; r < 4; ++r) {
          const int gm = bm0 + wm + mi * 16 + erow0 + r;
          float v = fmaxf(acc[mi][ni][r] + bv, 0.f);
          const _Float16 h = (_Float16)v;
          Oh[(size_t)gm * N + gn] = h;
          Ol[(size_t)gm * N + gn] = (_Float16)(v - (float)h);
        }
      }
  } else if constexpr (EPI == 1) {
#pragma unroll
    for (int mi = 0; mi < 4; ++mi)
#pragma unroll
      for (int r = 0; r < 4; ++r) {
        const int gm = bm0 + wm + mi * 16 + erow0 + r;
        const int tok = seq[tok0c + gm];
        const float* er = embed + (size_t)tok * kH;
#pragma unroll
        for (int ni = 0; ni < 4; ++ni) {
          const int gn = bn0 + wn + ni * 16 + (lane & 15);
          Xout[(size_t)gm * N + gn] = acc[mi][ni][r] + bias[gn] + er[gn];
        }
      }
  } else {
#pragma unroll
    for (int mi = 0; mi < 4; ++mi)
#pragma unroll
      for (int ni = 0; ni < 4; ++ni) {
        const int gn = bn0 + wn + ni * 16 + (lane & 15);
        const float bv = (gn < 256) ? bias[gn] : bias2[gn - 256];
#pragma unroll
        for (int r = 0; r < 4; ++r) {
          const int gm = bm0 + wm + mi * 16 + erow0 + r;
          const float v = acc[mi][ni][r] + bv;
          if (gn < 256) ks[(size_t)gm * 256 + gn] = v;
          else          ke[(size_t)gm * 256 + (gn - 256)] = v;
        }
      }
  }
}

// ---------------- LayerNorm: x fp32 -> hi/lo fp16
__global__ __launch_bounds__(256) void ln_split(
    const float* __restrict__ x, const float* __restrict__ g,
    const float* __restrict__ bta, _Float16* __restrict__ hh,
    _Float16* __restrict__ hl)
{
  const int wid  = threadIdx.x >> 6;
  const int lane = threadIdx.x & 63;
  const int ltok = blockIdx.x * 4 + wid;
  const float* xp = x + (size_t)ltok * kH;
  const float4 v0 = *(const float4*)(xp + lane * 8);
  const float4 v1 = *(const float4*)(xp + lane * 8 + 4);
  float s  = v0.x + v0.y + v0.z + v0.w + v1.x + v1.y + v1.z + v1.w;
  float ss = v0.x * v0.x + v0.y * v0.y + v0.z * v0.z + v0.w * v0.w +
             v1.x * v1.x + v1.y * v1.y + v1.z * v1.z + v1.w * v1.w;
#pragma unroll
  for (int m = 1; m < 64; m <<= 1) { s += __shfl_xor(s, m); ss += __shfl_xor(ss, m); }
  const float mu  = s * (1.f / kH);
  const float var = ss * (1.f / kH) - mu * mu;
  const float rs  = 1.f / sqrtf(var + 1e-5f);
  const float4 g0 = *(const float4*)(g + lane * 8);
  const float4 g1 = *(const float4*)(g + lane * 8 + 4);
  const float4 b0 = *(const float4*)(bta + lane * 8);
  const float4 b1 = *(const float4*)(bta + lane * 8 + 4);
  const float vv[8] = {v0.x, v0.y, v0.z, v0.w, v1.x, v1.y, v1.z, v1.w};
  const float gg[8] = {g0.x, g0.y, g0.z, g0.w, g1.x, g1.y, g1.z, g1.w};
  const float bb[8] = {b0.x, b0.y, b0.z, b0.w, b1.x, b1.y, b1.z, b1.w};
  union { _Float16 h[8]; uint4 u; } ph, pl;
#pragma unroll
  for (int i = 0; i < 8; ++i) {
    const float o = (vv[i] - mu) * rs * gg[i] + bb[i];
    fsplit(o, ph.h[i], pl.h[i]);
  }
  *(uint4*)(hh + (size_t)ltok * kH + lane * 8) = ph.u;
  *(uint4*)(hl + (size_t)ltok * kH + lane * 8) = pl.u;
}

// ---------------- chunked WY delta-rule scan (v11: lift the VGPR cap).
// r4-r6 post-mortem: __launch_bounds__(256,2)'s register tier (128) forced
// ~56 regs of scratch spill (WRITE_SIZE 304 vs 139 MB no-spill baseline).
// Occupancy is grid+LDS limited at 2 blocks/CU REGARDLESS (58KB LDS -> 2;
// 512 WGs / 256 CUs = 2), so VGPR up to 256 costs nothing. v11 relaxes to
// (256,1) and reinstates the kvp[16] solve prefetch (r4's latency hiding
// that was spill-poisoned). Body otherwise = v9 (best measured: 627us).
struct PhA1 { _Float16 Kph[64][72], Kpl[64][72]; };                 // 18432 B
struct PhB2 { float Rr[64][66]; _Float16 Uh[64][72], Ul[64][72]; }; // 35328 B
union  ShU1 { PhA1 a; PhB2 b; };
struct SGS  { _Float16 Sph[64][72], Spl[64][72]; };                 // 18432 B
union  ShU2 { SGS s; float Gm[64][66]; float cred[4][64]; };

__global__ __launch_bounds__(256, 1) void scan_chunked(
    const float* __restrict__ ks, const float* __restrict__ ke,
    const float* __restrict__ wts, float* __restrict__ c_out)
{
  __shared__ ShU1 u1;
  __shared__ ShU2 u2;
  __shared__ float aS[64], wS[64];
  __shared__ float UbS[16][64];      // fp32 U block for the parallel update

  const int tid  = threadIdx.x;
  const int lane = tid & 63;
  const int wv   = tid >> 6;
  const int l15  = lane & 15;
  const int quad = lane >> 4;
  const int wg   = blockIdx.x;
  const int b    = wg >> 3;
  const int mat  = (wg >> 2) & 1;
  const int q    = wg & 3;
  const int j0   = q * 64;
  const float* kb = (mat ? ke : ks) + (size_t)b * ((size_t)kL * kHalf);

  f32x4 S[16];
#pragma unroll
  for (int i = 0; i < 16; ++i) S[i] = {0.f, 0.f, 0.f, 0.f};

  const int stk = tid >> 2;          // staging token 0..63
  const int dg  = (tid & 3) * 16;    // staging col group
  const float* stgbase = kb + (size_t)stk * kHalf + dg;

  // chunk-level prefetch of panel 0 (plain registers, persists across phases)
  float4 pw0 = *(const float4*)(stgbase);
  float4 pw1 = *(const float4*)(stgbase + 4);
  float4 pw2 = *(const float4*)(stgbase + 8);
  float4 pw3 = *(const float4*)(stgbase + 12);

  for (int ck = 0; ck < 16; ++ck) {
    const int tok0 = ck * 64;
    float ssq = 0.f;
    f32x4 Qa[4], Ga[4];
#pragma unroll
    for (int i = 0; i < 4; ++i) { Qa[i] = {0.f,0.f,0.f,0.f}; Ga[i] = {0.f,0.f,0.f,0.f}; }

    __syncthreads();   // B0: prev chunk's Uh/Ul readers done (Kbuf aliases)

    {  // stage prefetched panel 0 (no memory wait: data already in regs)
      const float vv[16] = {pw0.x,pw0.y,pw0.z,pw0.w, pw1.x,pw1.y,pw1.z,pw1.w,
                            pw2.x,pw2.y,pw2.z,pw2.w, pw3.x,pw3.y,pw3.z,pw3.w};
      union { _Float16 h[16]; uint4 u[2]; } ph, pl;
#pragma unroll
      for (int i = 0; i < 16; ++i) { fsplit(vv[i], ph.h[i], pl.h[i]); ssq += vv[i]*vv[i]; }
      *(uint4*)&u1.a.Kph[stk][dg]     = ph.u[0];
      *(uint4*)&u1.a.Kph[stk][dg + 8] = ph.u[1];
      *(uint4*)&u1.a.Kpl[stk][dg]     = pl.u[0];
      *(uint4*)&u1.a.Kpl[stk][dg + 8] = pl.u[1];
    }
    if (wv == 0) {  // stage S panel 0 (dims 0..63): [col][dim] hi/lo
#pragma unroll
      for (int mi = 0; mi < 4; ++mi)
#pragma unroll
        for (int nt = 0; nt < 4; ++nt) {
          const f32x4 v = S[mi * 4 + nt];
          union { _Float16 h[4]; uint2 u; } qh, ql;
#pragma unroll
          for (int r = 0; r < 4; ++r) fsplit(v[r], qh.h[r], ql.h[r]);
          *(uint2*)&u2.s.Sph[nt * 16 + l15][mi * 16 + quad * 4] = qh.u;
          *(uint2*)&u2.s.Spl[nt * 16 + l15][mi * 16 + quad * 4] = ql.u;
        }
    }
    __syncthreads();   // B1

    for (int p = 0; p < 4; ++p) {
      float4 pv0, pv1, pv2, pv3;     // next-panel prefetch, plain registers
      if (p < 3) {
        const float* src = stgbase + (size_t)tok0 * kHalf + (p + 1) * 64;
        pv0 = *(const float4*)(src);
        pv1 = *(const float4*)(src + 4);
        pv2 = *(const float4*)(src + 8);
        pv3 = *(const float4*)(src + 12);
      }
#pragma unroll
      for (int kit = 0; kit < 2; ++kit) {
        const int ko = kit * 32 + quad * 8;
        const f16x8 ah = *(const f16x8*)&u1.a.Kph[wv * 16 + l15][ko];
        const f16x8 al = *(const f16x8*)&u1.a.Kpl[wv * 16 + l15][ko];
#pragma unroll
        for (int nt = 0; nt < 4; ++nt) {
          const f16x8 bh = *(const f16x8*)&u2.s.Sph[nt * 16 + l15][ko];
          const f16x8 bl = *(const f16x8*)&u2.s.Spl[nt * 16 + l15][ko];
          Qa[nt] = __builtin_amdgcn_mfma_f32_16x16x32_f16(ah, bh, Qa[nt], 0, 0, 0);
          Qa[nt] = __builtin_amdgcn_mfma_f32_16x16x32_f16(ah, bl, Qa[nt], 0, 0, 0);
          Qa[nt] = __builtin_amdgcn_mfma_f32_16x16x32_f16(al, bh, Qa[nt], 0, 0, 0);
        }
#pragma unroll
        for (int nt = 0; nt < 4; ++nt) {
          const f16x8 bh = *(const f16x8*)&u1.a.Kph[nt * 16 + l15][ko];
          const f16x8 bl = *(const f16x8*)&u1.a.Kpl[nt * 16 + l15][ko];
          Ga[nt] = __builtin_amdgcn_mfma_f32_16x16x32_f16(ah, bh, Ga[nt], 0, 0, 0);
          Ga[nt] = __builtin_amdgcn_mfma_f32_16x16x32_f16(ah, bl, Ga[nt], 0, 0, 0);
          Ga[nt] = __builtin_amdgcn_mfma_f32_16x16x32_f16(al, bh, Ga[nt], 0, 0, 0);
        }
      }
      __syncthreads();   // B2: Sbuf + Kbuf reads done
      if (p < 3) {
        const float vv[16] = {pv0.x,pv0.y,pv0.z,pv0.w, pv1.x,pv1.y,pv1.z,pv1.w,
                              pv2.x,pv2.y,pv2.z,pv2.w, pv3.x,pv3.y,pv3.z,pv3.w};
        union { _Float16 h[16]; uint4 u[2]; } ph, pl;
#pragma unroll
        for (int i = 0; i < 16; ++i) { fsplit(vv[i], ph.h[i], pl.h[i]); ssq += vv[i]*vv[i]; }
        *(uint4*)&u1.a.Kph[stk][dg]     = ph.u[0];
        *(uint4*)&u1.a.Kph[stk][dg + 8] = ph.u[1];
        *(uint4*)&u1.a.Kpl[stk][dg]     = pl.u[0];
        *(uint4*)&u1.a.Kpl[stk][dg + 8] = pl.u[1];
        if (wv == p + 1) {  // stage S panel p+1
#pragma unroll
          for (int mi = 0; mi < 4; ++mi)
#pragma unroll
            for (int nt = 0; nt < 4; ++nt) {
              const f32x4 v = S[mi * 4 + nt];
              union { _Float16 h[4]; uint2 u; } qh, ql;
#pragma unroll
              for (int r = 0; r < 4; ++r) fsplit(v[r], qh.h[r], ql.h[r]);
              *(uint2*)&u2.s.Sph[nt * 16 + l15][mi * 16 + quad * 4] = qh.u;
              *(uint2*)&u2.s.Spl[nt * 16 + l15][mi * 16 + quad * 4] = ql.u;
            }
        }
        __syncthreads();   // B3
      }
    }

    // fused invnorm
    ssq += __shfl_xor(ssq, 1);
    ssq += __shfl_xor(ssq, 2);
    if ((tid & 3) == 0) {
      const float w = mat ? wts[tok0 + stk] : 1.f;
      wS[stk] = w;
      aS[stk] = w / (ssq + 1e-6f);
    }

    // Q -> Rr[t][col] ; G -> Gm  (aliased regions; B2(p=3) separated reads)
#pragma unroll
    for (int nt = 0; nt < 4; ++nt) {
#pragma unroll
      for (int r = 0; r < 4; ++r)
        u1.b.Rr[wv * 16 + quad * 4 + r][nt * 16 + l15] = Qa[nt][r];
      *(float4*)&u2.Gm[nt * 16 + l15][wv * 16 + quad * 4] = *(const float4*)&Ga[nt];
    }
    // prefetch S-update A-fragments (K^T), consumed after the solve
    f16x8 uah[8], ual[8];
#pragma unroll
    for (int mi = 0; mi < 4; ++mi)
#pragma unroll
      for (int kit = 0; kit < 2; ++kit) {
        union { _Float16 h[8]; f16x8 v; } Ph, Pl;
        const int drow = 64 * wv + mi * 16 + l15;
#pragma unroll
        for (int jj = 0; jj < 8; ++jj) {
          const float v = kb[(size_t)(tok0 + kit * 32 + quad * 8 + jj) * kHalf + drow];
          fsplit(v, Ph.h[jj], Pl.h[jj]);
        }
        uah[mi * 2 + kit] = Ph.v;
        ual[mi * 2 + kit] = Pl.v;
      }
    // kv prefetch for solve block 0, issued before B4 (hidden by barrier wait)
    float kvp[16];
    if (tid < 64) {
#pragma unroll
      for (int i = 0; i < 16; ++i)
        kvp[i] = kb[(size_t)(tok0 + i) * kHalf + j0 + tid];
    }
    __syncthreads();   // B4: Rr/Gm/aS/wS visible

    // blocked triangular solve, 16-token blocks as two 8-wide sub-steps:
    // wave 0 does the serial diagonal work; ALL waves apply the rank-16
    // trailing update. kv loads pipelined one block ahead.
    for (int blk = 0; blk < 4; ++blk) {
      const int t0 = blk * 16;
      if (tid < 64) {
        const int j = tid;
        float kvA[8], kvB[8];
#pragma unroll
        for (int i = 0; i < 8; ++i) { kvA[i] = kvp[i]; kvB[i] = kvp[8 + i]; }
        if (blk < 3) {   // issue next block's kv loads; hide under solve+update
#pragma unroll
          for (int i = 0; i < 16; ++i)
            kvp[i] = kb[(size_t)(tok0 + t0 + 16 + i) * kHalf + j0 + j];
        }
        // sub-step A: tokens t0 .. t0+7
        float rlA[8], ubA[8];
#pragma unroll
        for (int i = 0; i < 8; ++i) rlA[i] = u1.b.Rr[t0 + i][j];
#pragma unroll
        for (int i = 0; i < 8; ++i) {
          const int t = t0 + i;
          const float u = wS[t] * kvA[i] - aS[t] * rlA[i];
          ubA[i] = u;
#pragma unroll
          for (int i2 = i + 1; i2 < 8; ++i2) rlA[i2] += u2.Gm[t0 + i2][t] * u;
        }
        union { _Float16 h[8]; uint4 u4; } uh, ul;
#pragma unroll
        for (int i = 0; i < 8; ++i) fsplit(ubA[i], uh.h[i], ul.h[i]);
        *(uint4*)&u1.b.Uh[j][t0] = uh.u4;
        *(uint4*)&u1.b.Ul[j][t0] = ul.u4;
#pragma unroll
        for (int i = 0; i < 8; ++i) UbS[i][j] = ubA[i];
        // sub-step B: tokens t0+8 .. t0+15 (rank-8 ubA applied in-wave)
        float rlB[8], ubB[8];
#pragma unroll
        for (int i = 0; i < 8; ++i) rlB[i] = u1.b.Rr[t0 + 8 + i][j];
#pragma unroll
        for (int i = 0; i < 8; ++i) {
          const float4 g0 = *(const float4*)&u2.Gm[t0 + 8 + i][t0];
          const float4 g1 = *(const float4*)&u2.Gm[t0 + 8 + i][t0 + 4];
          rlB[i] += g0.x*ubA[0] + g0.y*ubA[1] + g0.z*ubA[2] + g0.w*ubA[3]
                  + g1.x*ubA[4] + g1.y*ubA[5] + g1.z*ubA[6] + g1.w*ubA[7];
        }
#pragma unroll
        for (int i = 0; i < 8; ++i) {
          const int t = t0 + 8 + i;
          float u = wS[t] * kvB[i] - aS[t] * rlB[i];
          if (ck == 15 && t == 63) u = 0.f;   // token L-1 is the query only
          ubB[i] = u;
#pragma unroll
          for (int i2 = i + 1; i2 < 8; ++i2) rlB[i2] += u2.Gm[t0 + 8 + i2][t] * u;
        }
#pragma unroll
        for (int i = 0; i < 8; ++i) fsplit(ubB[i], uh.h[i], ul.h[i]);
        *(uint4*)&u1.b.Uh[j][t0 + 8] = uh.u4;
        *(uint4*)&u1.b.Ul[j][t0 + 8] = ul.u4;
#pragma unroll
        for (int i = 0; i < 8; ++i) UbS[8 + i][j] = ubB[i];
      }
      __syncthreads();           // U block visible
      if (blk < 3) {
        float ubv[16];
#pragma unroll
        for (int i = 0; i < 16; ++i) ubv[i] = UbS[i][lane];
        for (int t2 = t0 + 16 + wv; t2 < 64; t2 += 4) {
          const float4 g0 = *(const float4*)&u2.Gm[t2][t0];
          const float4 g1 = *(const float4*)&u2.Gm[t2][t0 + 4];
          const float4 g2 = *(const float4*)&u2.Gm[t2][t0 + 8];
          const float4 g3 = *(const float4*)&u2.Gm[t2][t0 + 12];
          u1.b.Rr[t2][lane] +=
              g0.x*ubv[0]  + g0.y*ubv[1]  + g0.z*ubv[2]  + g0.w*ubv[3]
            + g1.x*ubv[4]  + g1.y*ubv[5]  + g1.z*ubv[6]  + g1.w*ubv[7]
            + g2.x*ubv[8]  + g2.y*ubv[9]  + g2.z*ubv[10] + g2.w*ubv[11]
            + g3.x*ubv[12] + g3.y*ubv[13] + g3.z*ubv[14] + g3.w*ubv[15];
        }
        __syncthreads();         // updated Rr visible for next diagonal step
      }
    }
    // (last barrier above == B5: Uh/Ul visible)

    // prefetch next chunk's panel 0 BEFORE the S-update MFMA phase; the
    // ~96 MFMAs + B0 wait hide the HBM latency.
    if (ck < 15) {
      const float* src = stgbase + (size_t)(tok0 + 64) * kHalf;
      pw0 = *(const float4*)(src);
      pw1 = *(const float4*)(src + 4);
      pw2 = *(const float4*)(src + 8);
      pw3 = *(const float4*)(src + 12);
    }

    // S += K^T U
#pragma unroll
    for (int kit = 0; kit < 2; ++kit) {
      const int ko = kit * 32 + quad * 8;
#pragma unroll
      for (int nt = 0; nt < 4; ++nt) {
        const f16x8 bh = *(const f16x8*)&u1.b.Uh[nt * 16 + l15][ko];
        const f16x8 bl = *(const f16x8*)&u1.b.Ul[nt * 16 + l15][ko];
#pragma unroll
        for (int mi = 0; mi < 4; ++mi) {
          f32x4 s = S[mi * 4 + nt];
          s = __builtin_amdgcn_mfma_f32_16x16x32_f16(uah[mi * 2 + kit], bh, s, 0, 0, 0);
          s = __builtin_amdgcn_mfma_f32_16x16x32_f16(uah[mi * 2 + kit], bl, s, 0, 0, 0);
          s = __builtin_amdgcn_mfma_f32_16x16x32_f16(ual[mi * 2 + kit], bh, s, 0, 0, 0);
          S[mi * 4 + nt] = s;
        }
      }
    }
  }

  // readout: c[col] = sum_rows S[row][col] * k_last[row]
  float part[4] = {0.f, 0.f, 0.f, 0.f};
#pragma unroll
  for (int mi = 0; mi < 4; ++mi) {
    float klr[4];
#pragma unroll
    for (int r = 0; r < 4; ++r)
      klr[r] = kb[(size_t)(kL - 1) * kHalf + 64 * wv + mi * 16 + quad * 4 + r];
#pragma unroll
    for (int nt = 0; nt < 4; ++nt)
#pragma unroll
      for (int r = 0; r < 4; ++r) part[nt] += S[mi * 4 + nt][r] * klr[r];
  }
#pragma unroll
  for (int nt = 0; nt < 4; ++nt) {
    part[nt] += __shfl_xor(part[nt], 16);
    part[nt] += __shfl_xor(part[nt], 32);
  }
  __syncthreads();   // all prior LDS reads done before cred aliases Gm/Sbuf
  if (lane < 16) {
#pragma unroll
    for (int nt = 0; nt < 4; ++nt) u2.cred[wv][nt * 16 + l15] = part[nt];
  }
  __syncthreads();
  if (tid < 64) {
    const float c = u2.cred[0][tid] + u2.cred[1][tid] + u2.cred[2][tid] + u2.cred[3][tid];
    c_out[(size_t)b * 512 + mat * 256 + j0 + tid] = c;
  }
}

// ---------------- output GEMM: (64 x 512) @ (512 x 32000) + out_b -> fp32
__global__ __launch_bounds__(256) void out_gemm(
    const float* __restrict__ A, const float* __restrict__ Bm,
    const float* __restrict__ bias, float* __restrict__ C)
{
  __shared__ float As[16][64];
  __shared__ float Bs[16][128];
  const int tid = threadIdx.x;
  const int bn0 = blockIdx.x * 128;
  const int tm = tid >> 4, tn = tid & 15;
  float acc[4][8];
#pragma unroll
  for (int i = 0; i < 4; ++i)
#pragma unroll
    for (int j = 0; j < 8; ++j) acc[i][j] = 0.f;

  const int am  = tid & 63;
  const int ak  = (tid >> 6) * 4;
  const int bkr = tid >> 5;
  const int bcg = (tid & 31) * 4;

  for (int k0 = 0; k0 < kH; k0 += 16) {
    const float4 a0 = *(const float4*)(A + (size_t)am * kH + k0 + ak);
    const float4 b0 = *(const float4*)(Bm + (size_t)(k0 + bkr) * kV + bn0 + bcg);
    const float4 b1 = *(const float4*)(Bm + (size_t)(k0 + bkr + 8) * kV + bn0 + bcg);
    __syncthreads();
    As[ak + 0][am] = a0.x; As[ak + 1][am] = a0.y;
    As[ak + 2][am] = a0.z; As[ak + 3][am] = a0.w;
    *(float4*)&Bs[bkr][bcg]     = b0;
    *(float4*)&Bs[bkr + 8][bcg] = b1;
    __syncthreads();
#pragma unroll
    for (int kk = 0; kk < 16; ++kk) {
      const float4 aA = *(const float4*)&As[kk][tm * 4];
      const float4 bA = *(const float4*)&Bs[kk][tn * 4];
      const float4 bB = *(const float4*)&Bs[kk][64 + tn * 4];
      const float av[4] = {aA.x, aA.y, aA.z, aA.w};
      const float bv[8] = {bA.x, bA.y, bA.z, bA.w, bB.x, bB.y, bB.z, bB.w};
#pragma unroll
      for (int i = 0; i < 4; ++i)
#pragma unroll
        for (int j = 0; j < 8; ++j) acc[i][j] += av[i] * bv[j];
    }
  }

#pragma unroll
  for (int i = 0; i < 4; ++i) {
    const int row = tm * 4 + i;
#pragma unroll
    for (int hh = 0; hh < 2; ++hh) {
      const int n0 = bn0 + tn * 4 + hh * 64;
      const float4 bb = *(const float4*)(bias + n0);
      float4 o;
      o.x = acc[i][hh * 4 + 0] + bb.x;
      o.y = acc[i][hh * 4 + 1] + bb.y;
      o.z = acc[i][hh * 4 + 2] + bb.z;
      o.w = acc[i][hh * 4 + 3] + bb.w;
      *(float4*)(C + (size_t)row * kV + n0) = o;
    }
  }
}

}  // namespace

extern "C" void kernel_launch(void* const* d_in, const int* in_sizes, int n_in,
                              void* d_out, int out_size, void* d_ws, size_t ws_size,
                              hipStream_t stream)
{
  const int*   seq     = (const int*)  d_in[0];
  const float* embed   = (const float*)d_in[1];
  const float* w1      = (const float*)d_in[2];
  const float* b1      = (const float*)d_in[3];
  const float* w2      = (const float*)d_in[4];
  const float* b2      = (const float*)d_in[5];
  const float* ln_g    = (const float*)d_in[6];
  const float* ln_b    = (const float*)d_in[7];
  const float* sem_w   = (const float*)d_in[8];
  const float* sem_b   = (const float*)d_in[9];
  const float* epi_w   = (const float*)d_in[10];
  const float* epi_b   = (const float*)d_in[11];
  const float* out_w   = (const float*)d_in[12];
  const float* out_b   = (const float*)d_in[13];
  const float* pos_emb = (const float*)d_in[14];
  const float* pos_w   = (const float*)d_in[15];
  const float* pos_b   = (const float*)d_in[16];
  float* out = (float*)d_out;

  // chunk size: 16384 needs 240.3 MB of ws; fall back to 8192 if tight.
  // ws_size is constant per process -> deterministic, graph-capture-safe.
  const int chunkN = (ws_size >= (size_t)240500000) ? 16384 : 8192;
  const int nch    = kTok / chunkN;

  char* p = (char*)d_ws;
  _Float16* w1th = (_Float16*)p; p += (size_t)1024 * 512 * 2;
  _Float16* w1tl = (_Float16*)p; p += (size_t)1024 * 512 * 2;
  _Float16* w2th = (_Float16*)p; p += (size_t)512 * 1024 * 2;
  _Float16* w2tl = (_Float16*)p; p += (size_t)512 * 1024 * 2;
  _Float16* wseh = (_Float16*)p; p += (size_t)512 * 512 * 2;
  _Float16* wsel = (_Float16*)p; p += (size_t)512 * 512 * 2;
  _Float16* t1h  = (_Float16*)p; p += (size_t)chunkN * 1024 * 2;
  _Float16* t1l  = (_Float16*)p; p += (size_t)chunkN * 1024 * 2;
  float*    x    = (float*)p;    p += (size_t)chunkN * kH * 4;
  float*    ks   = (float*)p;    p += (size_t)kTok * kHalf * 4;
  float*    ke   = (float*)p;    p += (size_t)kTok * kHalf * 4;
  float*    wts  = (float*)p;    p += (size_t)kL * 4;
  float*    cout_= (float*)p;    p += (size_t)kB * 512 * 4;
  _Float16* hh   = t1h;          // alias: t1 dead once x is written
  _Float16* hl   = t1l;

  pos_kernel<<<dim3((kL + 255) / 256), dim3(256), 0, stream>>>(pos_emb, pos_w, pos_b, wts);
  transpose_split<<<dim3(1024 * 512 / 256), dim3(256), 0, stream>>>(w1, w1th, w1tl, 1024, 9);
  transpose_split<<<dim3(512 * 1024 / 256), dim3(256), 0, stream>>>(w2, w2th, w2tl, 512, 10);
  transpose_split<<<dim3(256 * 512 / 256), dim3(256), 0, stream>>>(sem_w, wseh, wsel, 256, 9);
  transpose_split<<<dim3(256 * 512 / 256), dim3(256), 0, stream>>>(
      epi_w, wseh + (size_t)256 * 512, wsel + (size_t)256 * 512, 256, 9);

  for (int c = 0; c < nch; ++c) {
    const int tok0 = c * chunkN;
    hgemm<0><<<dim3(1024 / 128, chunkN / 128), dim3(256), 0, stream>>>(
        seq, embed, nullptr, nullptr, w1th, w1tl, b1, nullptr,
        nullptr, t1h, t1l, nullptr, nullptr, 512, 1024, tok0);
    hgemm<1><<<dim3(512 / 128, chunkN / 128), dim3(256), 0, stream>>>(
        seq, embed, t1h, t1l, w2th, w2tl, b2, nullptr,
        x, nullptr, nullptr, nullptr, nullptr, 1024, 512, tok0);
    ln_split<<<dim3(chunkN / 4), dim3(256), 0, stream>>>(x, ln_g, ln_b, hh, hl);
    hgemm<2><<<dim3(512 / 128, chunkN / 128), dim3(256), 0, stream>>>(
        seq, embed, hh, hl, wseh, wsel, sem_b, epi_b,
        nullptr, nullptr, nullptr, ks + (size_t)tok0 * kHalf, ke + (size_t)tok0 * kHalf,
        512, 512, tok0);
  }

  scan_chunked<<<dim3(512), dim3(256), 0, stream>>>(ks, ke, wts, cout_);
  out_gemm<<<dim3(kV / 128), dim3(256), 0, stream>>>(cout_, out_w, out_b, out);

  (void)in_sizes; (void)n_in; (void)out_size;
}

// Round 9
// 1372.668 us; speedup vs baseline: 1.2316x; 1.2316x over previous
//
#include <hip/hip_runtime.h>
#include <hip/hip_bf16.h>
#include <math.h>

namespace {

constexpr int kH     = 512;
constexpr int kL     = 1024;
constexpr int kB     = 64;
constexpr int kHalf  = 256;
constexpr int kV     = 32000;
constexpr int kTok   = kB * kL;     // 65536

using f32x4 = __attribute__((ext_vector_type(4))) float;
using f16x8 = __attribute__((ext_vector_type(8))) _Float16;

__device__ inline void fsplit(float v, _Float16& h, _Float16& l) {
  h = (_Float16)v;
  l = (_Float16)(v - (float)h);
}

// async global->LDS, 16B per lane; dest = wave-uniform base + lane*16
#define GLD16(dst, src) \
  __builtin_amdgcn_global_load_lds( \
      (const __attribute__((address_space(1))) void*)(src), \
      (__attribute__((address_space(3))) void*)(dst), 16, 0, 0)

// ---------------- positional weights
__global__ void pos_kernel(const float* __restrict__ pos_emb,
                           const float* __restrict__ pos_w,
                           const float* __restrict__ pos_b,
                           float* __restrict__ wts)
{
  int t = blockIdx.x * blockDim.x + threadIdx.x;
  if (t >= kL) return;
  float z = pos_b[0];
#pragma unroll
  for (int p = 0; p < 16; ++p) z += pos_emb[t * 16 + p] * pos_w[p];
  wts[t] = 1.f / (1.f + expf(-z));
}

// ---------------- transpose + hi/lo fp16 split: W[K][N] fp32 -> Th/Tl[N][K]
__global__ __launch_bounds__(256) void transpose_split(
    const float* __restrict__ W, _Float16* __restrict__ Th,
    _Float16* __restrict__ Tl, int N, int kshift)
{
  const int idx = blockIdx.x * 256 + threadIdx.x;
  const int K = 1 << kshift;
  const int k = idx & (K - 1);
  const int n = idx >> kshift;
  const float w = W[(size_t)k * N + n];
  const _Float16 h = (_Float16)w;
  Th[idx] = h;
  Tl[idx] = (_Float16)(w - (float)h);
}

// ---------------- split-fp16 MFMA GEMM: C[M,N] = A[M,K] @ (Bh+Bl)[N,K]^T
// v2: operand staging via global_load_lds width=16 (r7: −30us vs reg-stage).
union HgemmLds {
  struct { _Float16 A[2][128][40]; _Float16 Bh[128][32]; _Float16 Bl[128][32]; } e0; // 36864 B
  struct { _Float16 G[4][128][32]; } e1;                                             // 32768 B
};

template <int EPI>
__global__ __launch_bounds__(256) void hgemm(
    const int* __restrict__ seq, const float* __restrict__ embed,
    const _Float16* __restrict__ Ah, const _Float16* __restrict__ Al,
    const _Float16* __restrict__ Bh, const _Float16* __restrict__ Bl,
    const float* __restrict__ bias, const float* __restrict__ bias2,
    float* __restrict__ Xout, _Float16* __restrict__ Oh, _Float16* __restrict__ Ol,
    float* __restrict__ ks, float* __restrict__ ke,
    int K, int N, int tok0c)
{
  __shared__ HgemmLds u;
  const int tid  = threadIdx.x;
  const int lane = tid & 63;
  const int wv   = tid >> 6;
  const int wm   = (wv >> 1) * 64;
  const int wn   = (wv & 1) * 64;
  const int bm0  = blockIdx.y * 128;
  const int bn0  = blockIdx.x * 128;

  f32x4 acc[4][4];
#pragma unroll
  for (int i = 0; i < 4; ++i)
#pragma unroll
    for (int j = 0; j < 4; ++j) acc[i][j] = {0.f, 0.f, 0.f, 0.f};

  // gload lane geometry: lane l covers row (chunk + l>>2), bytes (l&3)*16
  const int glr = lane >> 2;
  const int glc = (lane & 3) * 8;          // halves
  const _Float16* gB0h = Bh + (size_t)(bn0 + wv * 32 + glr) * K + glc;
  const _Float16* gB0l = Bl + (size_t)(bn0 + wv * 32 + glr) * K + glc;
  const _Float16* gA0h = nullptr;
  const _Float16* gA0l = nullptr;
  const float*    gAe  = nullptr;
  const int sr = tid >> 1;                 // EPI0 A staging row
  const int sc = (tid & 1) << 4;
  if constexpr (EPI == 0) {
    const int tokrow = seq[tok0c + bm0 + sr];
    gAe = embed + (size_t)tokrow * kH + sc;
  } else {
    gA0h = Ah + (size_t)(bm0 + wv * 32 + glr) * K + glc;
    gA0l = Al + (size_t)(bm0 + wv * 32 + glr) * K + glc;
  }

  const int lrow = lane & 15;
  const int lk   = (lane >> 4) * 8;

  // wave-uniform LDS dest bases (halves)
  _Float16* dBh; _Float16* dBl;
  _Float16* dAh = nullptr; _Float16* dAl = nullptr;
  if constexpr (EPI == 0) {
    dBh = &u.e0.Bh[0][0]; dBl = &u.e0.Bl[0][0];
  } else {
    dAh = &u.e1.G[0][0][0]; dAl = &u.e1.G[1][0][0];
    dBh = &u.e1.G[2][0][0]; dBl = &u.e1.G[3][0][0];
  }
  const int lo0 = (wv * 32) * 32;          // wave chunk 0 offset (halves)
  const int lo1 = (wv * 32 + 16) * 32;     // wave chunk 1

  for (int k0 = 0; k0 < K; k0 += 32) {
    if constexpr (EPI == 0) {
      // A loads issued before the barrier (overlap with prev MFMA phase)
      const float4 a0 = *(const float4*)(gAe + k0);
      const float4 a1 = *(const float4*)(gAe + k0 + 4);
      const float4 a2 = *(const float4*)(gAe + k0 + 8);
      const float4 a3 = *(const float4*)(gAe + k0 + 12);
      const float vv[16] = {a0.x,a0.y,a0.z,a0.w, a1.x,a1.y,a1.z,a1.w,
                            a2.x,a2.y,a2.z,a2.w, a3.x,a3.y,a3.z,a3.w};
      union { _Float16 h[16]; uint4 uu[2]; } ph, pl;
#pragma unroll
      for (int i = 0; i < 16; ++i) fsplit(vv[i], ph.h[i], pl.h[i]);
      __syncthreads();                     // prev LDS readers done
      GLD16(dBh + lo0, gB0h + k0);
      GLD16(dBh + lo1, gB0h + (size_t)16 * K + k0);
      GLD16(dBl + lo0, gB0l + k0);
      GLD16(dBl + lo1, gB0l + (size_t)16 * K + k0);
      *(uint4*)&u.e0.A[0][sr][sc]     = ph.uu[0];
      *(uint4*)&u.e0.A[0][sr][sc + 8] = ph.uu[1];
      *(uint4*)&u.e0.A[1][sr][sc]     = pl.uu[0];
      *(uint4*)&u.e0.A[1][sr][sc + 8] = pl.uu[1];
    } else {
      __syncthreads();                     // prev LDS readers done
      GLD16(dAh + lo0, gA0h + k0);
      GLD16(dAh + lo1, gA0h + (size_t)16 * K + k0);
      GLD16(dAl + lo0, gA0l + k0);
      GLD16(dAl + lo1, gA0l + (size_t)16 * K + k0);
      GLD16(dBh + lo0, gB0h + k0);
      GLD16(dBh + lo1, gB0h + (size_t)16 * K + k0);
      GLD16(dBl + lo0, gB0l + k0);
      GLD16(dBl + lo1, gB0l + (size_t)16 * K + k0);
    }
    __syncthreads();                       // drains vmcnt: tiles ready

    f16x8 fBh[4], fBl[4];
#pragma unroll
    for (int ni = 0; ni < 4; ++ni) {
      if constexpr (EPI == 0) {
        fBh[ni] = *(const f16x8*)&u.e0.Bh[wn + ni * 16 + lrow][lk];
        fBl[ni] = *(const f16x8*)&u.e0.Bl[wn + ni * 16 + lrow][lk];
      } else {
        fBh[ni] = *(const f16x8*)&u.e1.G[2][wn + ni * 16 + lrow][lk];
        fBl[ni] = *(const f16x8*)&u.e1.G[3][wn + ni * 16 + lrow][lk];
      }
    }
#pragma unroll
    for (int mi = 0; mi < 4; ++mi) {
      f16x8 ah, al;
      if constexpr (EPI == 0) {
        ah = *(const f16x8*)&u.e0.A[0][wm + mi * 16 + lrow][lk];
        al = *(const f16x8*)&u.e0.A[1][wm + mi * 16 + lrow][lk];
      } else {
        ah = *(const f16x8*)&u.e1.G[0][wm + mi * 16 + lrow][lk];
        al = *(const f16x8*)&u.e1.G[1][wm + mi * 16 + lrow][lk];
      }
#pragma unroll
      for (int ni = 0; ni < 4; ++ni) {
        acc[mi][ni] = __builtin_amdgcn_mfma_f32_16x16x32_f16(ah, fBh[ni], acc[mi][ni], 0, 0, 0);
        acc[mi][ni] = __builtin_amdgcn_mfma_f32_16x16x32_f16(ah, fBl[ni], acc[mi][ni], 0, 0, 0);
        acc[mi][ni] = __builtin_amdgcn_mfma_f32_16x16x32_f16(al, fBh[ni], acc[mi][ni], 0, 0, 0);
      }
    }
  }

  const int erow0 = (lane >> 4) * 4;
  if constexpr (EPI == 0) {
#pragma unroll
    for (int mi = 0; mi < 4; ++mi)
#pragma unroll
      for (int ni = 0; ni < 4; ++ni) {
        const int gn = bn0 + wn + ni * 16 + (lane & 15);
        const float bv = bias[gn];
#pragma unroll
        for (int r = 0; r < 4; ++r) {
          const int gm = bm0 + wm + mi * 16 + erow0 + r;
          float v = fmaxf(acc[mi][ni][r] + bv, 0.f);
          const _Float16 h = (_Float16)v;
          Oh[(size_t)gm * N + gn] = h;
          Ol[(size_t)gm * N + gn] = (_Float16)(v - (float)h);
        }
      }
  } else if constexpr (EPI == 1) {
#pragma unroll
    for (int mi = 0; mi < 4; ++mi)
#pragma unroll
      for (int r = 0; r < 4; ++r) {
        const int gm = bm0 + wm + mi * 16 + erow0 + r;
        const int tok = seq[tok0c + gm];
        const float* er = embed + (size_t)tok * kH;
#pragma unroll
        for (int ni = 0; ni < 4; ++ni) {
          const int gn = bn0 + wn + ni * 16 + (lane & 15);
          Xout[(size_t)gm * N + gn] = acc[mi][ni][r] + bias[gn] + er[gn];
        }
      }
  } else {
#pragma unroll
    for (int mi = 0; mi < 4; ++mi)
#pragma unroll
      for (int ni = 0; ni < 4; ++ni) {
        const int gn = bn0 + wn + ni * 16 + (lane & 15);
        const float bv = (gn < 256) ? bias[gn] : bias2[gn - 256];
#pragma unroll
        for (int r = 0; r < 4; ++r) {
          const int gm = bm0 + wm + mi * 16 + erow0 + r;
          const float v = acc[mi][ni][r] + bv;
          if (gn < 256) ks[(size_t)gm * 256 + gn] = v;
          else          ke[(size_t)gm * 256 + (gn - 256)] = v;
        }
      }
  }
}

// ---------------- LayerNorm: x fp32 -> hi/lo fp16
__global__ __launch_bounds__(256) void ln_split(
    const float* __restrict__ x, const float* __restrict__ g,
    const float* __restrict__ bta, _Float16* __restrict__ hh,
    _Float16* __restrict__ hl)
{
  const int wid  = threadIdx.x >> 6;
  const int lane = threadIdx.x & 63;
  const int ltok = blockIdx.x * 4 + wid;
  const float* xp = x + (size_t)ltok * kH;
  const float4 v0 = *(const float4*)(xp + lane * 8);
  const float4 v1 = *(const float4*)(xp + lane * 8 + 4);
  float s  = v0.x + v0.y + v0.z + v0.w + v1.x + v1.y + v1.z + v1.w;
  float ss = v0.x * v0.x + v0.y * v0.y + v0.z * v0.z + v0.w * v0.w +
             v1.x * v1.x + v1.y * v1.y + v1.z * v1.z + v1.w * v1.w;
#pragma unroll
  for (int m = 1; m < 64; m <<= 1) { s += __shfl_xor(s, m); ss += __shfl_xor(ss, m); }
  const float mu  = s * (1.f / kH);
  const float var = ss * (1.f / kH) - mu * mu;
  const float rs  = 1.f / sqrtf(var + 1e-5f);
  const float4 g0 = *(const float4*)(g + lane * 8);
  const float4 g1 = *(const float4*)(g + lane * 8 + 4);
  const float4 b0 = *(const float4*)(bta + lane * 8);
  const float4 b1 = *(const float4*)(bta + lane * 8 + 4);
  const float vv[8] = {v0.x, v0.y, v0.z, v0.w, v1.x, v1.y, v1.z, v1.w};
  const float gg[8] = {g0.x, g0.y, g0.z, g0.w, g1.x, g1.y, g1.z, g1.w};
  const float bb[8] = {b0.x, b0.y, b0.z, b0.w, b1.x, b1.y, b1.z, b1.w};
  union { _Float16 h[8]; uint4 u; } ph, pl;
#pragma unroll
  for (int i = 0; i < 8; ++i) {
    const float o = (vv[i] - mu) * rs * gg[i] + bb[i];
    fsplit(o, ph.h[i], pl.h[i]);
  }
  *(uint4*)(hh + (size_t)ltok * kH + lane * 8) = ph.u;
  *(uint4*)(hl + (size_t)ltok * kH + lane * 8) = pl.u;
}

// ---------------- chunked WY delta-rule scan (v13: zero-spill at 2 waves/EU).
// r8 proved: (a) ALL prior WRITE traffic was spill (r8: WRITE=128B);
// (b) arch 216 + ~96 AGPR > 256 total -> 1 wave/SIMD -> 925us (occupancy
// dominates). Sweet spot = 2 waves/SIMD (total<=256) with no spill:
// amdgpu_waves_per_eu(2) caps total at 256 (launch_bounds(256,2) empirically
// capped arch at 128 -> 56-reg spill). Arch demand cut 216 -> ~168 by:
// (1) no pw[16] chunk-prefetch (panel-0 loaded after B0; ks/ke is L3-hot),
// (2) no kvp[16] (v9's direct kvA/kvB loads),
// (3) uah/ual built per-kit inside the S-update (32 live, was 64 across
//     the whole solve). Accumulation order preserved -> bit-identical.
struct PhA1 { _Float16 Kph[64][72], Kpl[64][72]; };                 // 18432 B
struct PhB2 { float Rr[64][66]; _Float16 Uh[64][72], Ul[64][72]; }; // 35328 B
union  ShU1 { PhA1 a; PhB2 b; };
struct SGS  { _Float16 Sph[64][72], Spl[64][72]; };                 // 18432 B
union  ShU2 { SGS s; float Gm[64][66]; float cred[4][64]; };

__global__
__attribute__((amdgpu_flat_work_group_size(256, 256), amdgpu_waves_per_eu(2)))
void scan_chunked(
    const float* __restrict__ ks, const float* __restrict__ ke,
    const float* __restrict__ wts, float* __restrict__ c_out)
{
  __shared__ ShU1 u1;
  __shared__ ShU2 u2;
  __shared__ float aS[64], wS[64];
  __shared__ float UbS[16][64];      // fp32 U block for the parallel update

  const int tid  = threadIdx.x;
  const int lane = tid & 63;
  const int wv   = tid >> 6;
  const int l15  = lane & 15;
  const int quad = lane >> 4;
  const int wg   = blockIdx.x;
  const int b    = wg >> 3;
  const int mat  = (wg >> 2) & 1;
  const int q    = wg & 3;
  const int j0   = q * 64;
  const float* kb = (mat ? ke : ks) + (size_t)b * ((size_t)kL * kHalf);

  f32x4 S[16];
#pragma unroll
  for (int i = 0; i < 16; ++i) S[i] = {0.f, 0.f, 0.f, 0.f};

  const int stk = tid >> 2;          // staging token 0..63
  const int dg  = (tid & 3) * 16;    // staging col group
  const float* stgbase = kb + (size_t)stk * kHalf + dg;

  for (int ck = 0; ck < 16; ++ck) {
    const int tok0 = ck * 64;
    float ssq = 0.f;
    f32x4 Qa[4], Ga[4];
#pragma unroll
    for (int i = 0; i < 4; ++i) { Qa[i] = {0.f,0.f,0.f,0.f}; Ga[i] = {0.f,0.f,0.f,0.f}; }

    __syncthreads();   // B0: prev chunk's Uh/Ul readers done (Kbuf aliases)

    {  // stage K panel 0 (ks/ke is L3-resident: ~low-hundreds cy exposed)
      const float* src = stgbase + (size_t)tok0 * kHalf;
      const float4 v0 = *(const float4*)(src);
      const float4 v1 = *(const float4*)(src + 4);
      const float4 v2 = *(const float4*)(src + 8);
      const float4 v3 = *(const float4*)(src + 12);
      const float vv[16] = {v0.x,v0.y,v0.z,v0.w, v1.x,v1.y,v1.z,v1.w,
                            v2.x,v2.y,v2.z,v2.w, v3.x,v3.y,v3.z,v3.w};
      union { _Float16 h[16]; uint4 u[2]; } ph, pl;
#pragma unroll
      for (int i = 0; i < 16; ++i) { fsplit(vv[i], ph.h[i], pl.h[i]); ssq += vv[i]*vv[i]; }
      *(uint4*)&u1.a.Kph[stk][dg]     = ph.u[0];
      *(uint4*)&u1.a.Kph[stk][dg + 8] = ph.u[1];
      *(uint4*)&u1.a.Kpl[stk][dg]     = pl.u[0];
      *(uint4*)&u1.a.Kpl[stk][dg + 8] = pl.u[1];
    }
    if (wv == 0) {  // stage S panel 0 (dims 0..63): [col][dim] hi/lo
#pragma unroll
      for (int mi = 0; mi < 4; ++mi)
#pragma unroll
        for (int nt = 0; nt < 4; ++nt) {
          const f32x4 v = S[mi * 4 + nt];
          union { _Float16 h[4]; uint2 u; } qh, ql;
#pragma unroll
          for (int r = 0; r < 4; ++r) fsplit(v[r], qh.h[r], ql.h[r]);
          *(uint2*)&u2.s.Sph[nt * 16 + l15][mi * 16 + quad * 4] = qh.u;
          *(uint2*)&u2.s.Spl[nt * 16 + l15][mi * 16 + quad * 4] = ql.u;
        }
    }
    __syncthreads();   // B1

    for (int p = 0; p < 4; ++p) {
      float4 pv0, pv1, pv2, pv3;     // next-panel prefetch, plain registers
      if (p < 3) {
        const float* src = stgbase + (size_t)tok0 * kHalf + (p + 1) * 64;
        pv0 = *(const float4*)(src);
        pv1 = *(const float4*)(src + 4);
        pv2 = *(const float4*)(src + 8);
        pv3 = *(const float4*)(src + 12);
      }
#pragma unroll
      for (int kit = 0; kit < 2; ++kit) {
        const int ko = kit * 32 + quad * 8;
        const f16x8 ah = *(const f16x8*)&u1.a.Kph[wv * 16 + l15][ko];
        const f16x8 al = *(const f16x8*)&u1.a.Kpl[wv * 16 + l15][ko];
#pragma unroll
        for (int nt = 0; nt < 4; ++nt) {
          const f16x8 bh = *(const f16x8*)&u2.s.Sph[nt * 16 + l15][ko];
          const f16x8 bl = *(const f16x8*)&u2.s.Spl[nt * 16 + l15][ko];
          Qa[nt] = __builtin_amdgcn_mfma_f32_16x16x32_f16(ah, bh, Qa[nt], 0, 0, 0);
          Qa[nt] = __builtin_amdgcn_mfma_f32_16x16x32_f16(ah, bl, Qa[nt], 0, 0, 0);
          Qa[nt] = __builtin_amdgcn_mfma_f32_16x16x32_f16(al, bh, Qa[nt], 0, 0, 0);
        }
#pragma unroll
        for (int nt = 0; nt < 4; ++nt) {
          const f16x8 bh = *(const f16x8*)&u1.a.Kph[nt * 16 + l15][ko];
          const f16x8 bl = *(const f16x8*)&u1.a.Kpl[nt * 16 + l15][ko];
          Ga[nt] = __builtin_amdgcn_mfma_f32_16x16x32_f16(ah, bh, Ga[nt], 0, 0, 0);
          Ga[nt] = __builtin_amdgcn_mfma_f32_16x16x32_f16(ah, bl, Ga[nt], 0, 0, 0);
          Ga[nt] = __builtin_amdgcn_mfma_f32_16x16x32_f16(al, bh, Ga[nt], 0, 0, 0);
        }
      }
      __syncthreads();   // B2: Sbuf + Kbuf reads done
      if (p < 3) {
        const float vv[16] = {pv0.x,pv0.y,pv0.z,pv0.w, pv1.x,pv1.y,pv1.z,pv1.w,
                              pv2.x,pv2.y,pv2.z,pv2.w, pv3.x,pv3.y,pv3.z,pv3.w};
        union { _Float16 h[16]; uint4 u[2]; } ph, pl;
#pragma unroll
        for (int i = 0; i < 16; ++i) { fsplit(vv[i], ph.h[i], pl.h[i]); ssq += vv[i]*vv[i]; }
        *(uint4*)&u1.a.Kph[stk][dg]     = ph.u[0];
        *(uint4*)&u1.a.Kph[stk][dg + 8] = ph.u[1];
        *(uint4*)&u1.a.Kpl[stk][dg]     = pl.u[0];
        *(uint4*)&u1.a.Kpl[stk][dg + 8] = pl.u[1];
        if (wv == p + 1) {  // stage S panel p+1
#pragma unroll
          for (int mi = 0; mi < 4; ++mi)
#pragma unroll
            for (int nt = 0; nt < 4; ++nt) {
              const f32x4 v = S[mi * 4 + nt];
              union { _Float16 h[4]; uint2 u; } qh, ql;
#pragma unroll
              for (int r = 0; r < 4; ++r) fsplit(v[r], qh.h[r], ql.h[r]);
              *(uint2*)&u2.s.Sph[nt * 16 + l15][mi * 16 + quad * 4] = qh.u;
              *(uint2*)&u2.s.Spl[nt * 16 + l15][mi * 16 + quad * 4] = ql.u;
            }
        }
        __syncthreads();   // B3
      }
    }

    // fused invnorm
    ssq += __shfl_xor(ssq, 1);
    ssq += __shfl_xor(ssq, 2);
    if ((tid & 3) == 0) {
      const float w = mat ? wts[tok0 + stk] : 1.f;
      wS[stk] = w;
      aS[stk] = w / (ssq + 1e-6f);
    }

    // Q -> Rr[t][col] ; G -> Gm  (aliased regions; B2(p=3) separated reads)
#pragma unroll
    for (int nt = 0; nt < 4; ++nt) {
#pragma unroll
      for (int r = 0; r < 4; ++r)
        u1.b.Rr[wv * 16 + quad * 4 + r][nt * 16 + l15] = Qa[nt][r];
      *(float4*)&u2.Gm[nt * 16 + l15][wv * 16 + quad * 4] = *(const float4*)&Ga[nt];
    }
    __syncthreads();   // B4: Rr/Gm/aS/wS visible

    // blocked triangular solve, 16-token blocks as two 8-wide sub-steps:
    // wave 0 does the serial diagonal work; ALL waves apply the rank-16
    // trailing update. kv loads are direct (L2-hot), no prefetch arrays.
    for (int blk = 0; blk < 4; ++blk) {
      const int t0 = blk * 16;
      if (tid < 64) {
        const int j = tid;
        float kvA[8], kvB[8];
#pragma unroll
        for (int i = 0; i < 8; ++i)
          kvA[i] = kb[(size_t)(tok0 + t0 + i) * kHalf + j0 + j];
#pragma unroll
        for (int i = 0; i < 8; ++i)
          kvB[i] = kb[(size_t)(tok0 + t0 + 8 + i) * kHalf + j0 + j];
        // sub-step A: tokens t0 .. t0+7
        float rlA[8], ubA[8];
#pragma unroll
        for (int i = 0; i < 8; ++i) rlA[i] = u1.b.Rr[t0 + i][j];
#pragma unroll
        for (int i = 0; i < 8; ++i) {
          const int t = t0 + i;
          const float u = wS[t] * kvA[i] - aS[t] * rlA[i];
          ubA[i] = u;
#pragma unroll
          for (int i2 = i + 1; i2 < 8; ++i2) rlA[i2] += u2.Gm[t0 + i2][t] * u;
        }
        union { _Float16 h[8]; uint4 u4; } uh, ul;
#pragma unroll
        for (int i = 0; i < 8; ++i) fsplit(ubA[i], uh.h[i], ul.h[i]);
        *(uint4*)&u1.b.Uh[j][t0] = uh.u4;
        *(uint4*)&u1.b.Ul[j][t0] = ul.u4;
#pragma unroll
        for (int i = 0; i < 8; ++i) UbS[i][j] = ubA[i];
        // sub-step B: tokens t0+8 .. t0+15 (rank-8 ubA applied in-wave)
        float rlB[8], ubB[8];
#pragma unroll
        for (int i = 0; i < 8; ++i) rlB[i] = u1.b.Rr[t0 + 8 + i][j];
#pragma unroll
        for (int i = 0; i < 8; ++i) {
          const float4 g0 = *(const float4*)&u2.Gm[t0 + 8 + i][t0];
          const float4 g1 = *(const float4*)&u2.Gm[t0 + 8 + i][t0 + 4];
          rlB[i] += g0.x*ubA[0] + g0.y*ubA[1] + g0.z*ubA[2] + g0.w*ubA[3]
                  + g1.x*ubA[4] + g1.y*ubA[5] + g1.z*ubA[6] + g1.w*ubA[7];
        }
#pragma unroll
        for (int i = 0; i < 8; ++i) {
          const int t = t0 + 8 + i;
          float u = wS[t] * kvB[i] - aS[t] * rlB[i];
          if (ck == 15 && t == 63) u = 0.f;   // token L-1 is the query only
          ubB[i] = u;
#pragma unroll
          for (int i2 = i + 1; i2 < 8; ++i2) rlB[i2] += u2.Gm[t0 + 8 + i2][t] * u;
        }
#pragma unroll
        for (int i = 0; i < 8; ++i) fsplit(ubB[i], uh.h[i], ul.h[i]);
        *(uint4*)&u1.b.Uh[j][t0 + 8] = uh.u4;
        *(uint4*)&u1.b.Ul[j][t0 + 8] = ul.u4;
#pragma unroll
        for (int i = 0; i < 8; ++i) UbS[8 + i][j] = ubB[i];
      }
      __syncthreads();           // U block visible
      if (blk < 3) {
        float ubv[16];
#pragma unroll
        for (int i = 0; i < 16; ++i) ubv[i] = UbS[i][lane];
        for (int t2 = t0 + 16 + wv; t2 < 64; t2 += 4) {
          const float4 g0 = *(const float4*)&u2.Gm[t2][t0];
          const float4 g1 = *(const float4*)&u2.Gm[t2][t0 + 4];
          const float4 g2 = *(const float4*)&u2.Gm[t2][t0 + 8];
          const float4 g3 = *(const float4*)&u2.Gm[t2][t0 + 12];
          u1.b.Rr[t2][lane] +=
              g0.x*ubv[0]  + g0.y*ubv[1]  + g0.z*ubv[2]  + g0.w*ubv[3]
            + g1.x*ubv[4]  + g1.y*ubv[5]  + g1.z*ubv[6]  + g1.w*ubv[7]
            + g2.x*ubv[8]  + g2.y*ubv[9]  + g2.z*ubv[10] + g2.w*ubv[11]
            + g3.x*ubv[12] + g3.y*ubv[13] + g3.z*ubv[14] + g3.w*ubv[15];
        }
        __syncthreads();         // updated Rr visible for next diagonal step
      }
    }
    // (last barrier above == B5: Uh/Ul visible)

    // S += K^T U; fragments built per-kit (32 VGPRs live, L2/L3-hot loads).
    // Same kit-major accumulation order as before -> bit-identical.
#pragma unroll
    for (int kit = 0; kit < 2; ++kit) {
      f16x8 uah[4], ual[4];
#pragma unroll
      for (int mi = 0; mi < 4; ++mi) {
        union { _Float16 h[8]; f16x8 v; } Ph, Pl;
        const int drow = 64 * wv + mi * 16 + l15;
#pragma unroll
        for (int jj = 0; jj < 8; ++jj) {
          const float v = kb[(size_t)(tok0 + kit * 32 + quad * 8 + jj) * kHalf + drow];
          fsplit(v, Ph.h[jj], Pl.h[jj]);
        }
        uah[mi] = Ph.v;
        ual[mi] = Pl.v;
      }
      const int ko = kit * 32 + quad * 8;
#pragma unroll
      for (int nt = 0; nt < 4; ++nt) {
        const f16x8 bh = *(const f16x8*)&u1.b.Uh[nt * 16 + l15][ko];
        const f16x8 bl = *(const f16x8*)&u1.b.Ul[nt * 16 + l15][ko];
#pragma unroll
        for (int mi = 0; mi < 4; ++mi) {
          f32x4 s = S[mi * 4 + nt];
          s = __builtin_amdgcn_mfma_f32_16x16x32_f16(uah[mi], bh, s, 0, 0, 0);
          s = __builtin_amdgcn_mfma_f32_16x16x32_f16(uah[mi], bl, s, 0, 0, 0);
          s = __builtin_amdgcn_mfma_f32_16x16x32_f16(ual[mi], bh, s, 0, 0, 0);
          S[mi * 4 + nt] = s;
        }
      }
    }
  }

  // readout: c[col] = sum_rows S[row][col] * k_last[row]
  float part[4] = {0.f, 0.f, 0.f, 0.f};
#pragma unroll
  for (int mi = 0; mi < 4; ++mi) {
    float klr[4];
#pragma unroll
    for (int r = 0; r < 4; ++r)
      klr[r] = kb[(size_t)(kL - 1) * kHalf + 64 * wv + mi * 16 + quad * 4 + r];
#pragma unroll
    for (int nt = 0; nt < 4; ++nt)
#pragma unroll
      for (int r = 0; r < 4; ++r) part[nt] += S[mi * 4 + nt][r] * klr[r];
  }
#pragma unroll
  for (int nt = 0; nt < 4; ++nt) {
    part[nt] += __shfl_xor(part[nt], 16);
    part[nt] += __shfl_xor(part[nt], 32);
  }
  __syncthreads();   // all prior LDS reads done before cred aliases Gm/Sbuf
  if (lane < 16) {
#pragma unroll
    for (int nt = 0; nt < 4; ++nt) u2.cred[wv][nt * 16 + l15] = part[nt];
  }
  __syncthreads();
  if (tid < 64) {
    const float c = u2.cred[0][tid] + u2.cred[1][tid] + u2.cred[2][tid] + u2.cred[3][tid];
    c_out[(size_t)b * 512 + mat * 256 + j0 + tid] = c;
  }
}

// ---------------- output GEMM: (64 x 512) @ (512 x 32000) + out_b -> fp32
__global__ __launch_bounds__(256) void out_gemm(
    const float* __restrict__ A, const float* __restrict__ Bm,
    const float* __restrict__ bias, float* __restrict__ C)
{
  __shared__ float As[16][64];
  __shared__ float Bs[16][128];
  const int tid = threadIdx.x;
  const int bn0 = blockIdx.x * 128;
  const int tm = tid >> 4, tn = tid & 15;
  float acc[4][8];
#pragma unroll
  for (int i = 0; i < 4; ++i)
#pragma unroll
    for (int j = 0; j < 8; ++j) acc[i][j] = 0.f;

  const int am  = tid & 63;
  const int ak  = (tid >> 6) * 4;
  const int bkr = tid >> 5;
  const int bcg = (tid & 31) * 4;

  for (int k0 = 0; k0 < kH; k0 += 16) {
    const float4 a0 = *(const float4*)(A + (size_t)am * kH + k0 + ak);
    const float4 b0 = *(const float4*)(Bm + (size_t)(k0 + bkr) * kV + bn0 + bcg);
    const float4 b1 = *(const float4*)(Bm + (size_t)(k0 + bkr + 8) * kV + bn0 + bcg);
    __syncthreads();
    As[ak + 0][am] = a0.x; As[ak + 1][am] = a0.y;
    As[ak + 2][am] = a0.z; As[ak + 3][am] = a0.w;
    *(float4*)&Bs[bkr][bcg]     = b0;
    *(float4*)&Bs[bkr + 8][bcg] = b1;
    __syncthreads();
#pragma unroll
    for (int kk = 0; kk < 16; ++kk) {
      const float4 aA = *(const float4*)&As[kk][tm * 4];
      const float4 bA = *(const float4*)&Bs[kk][tn * 4];
      const float4 bB = *(const float4*)&Bs[kk][64 + tn * 4];
      const float av[4] = {aA.x, aA.y, aA.z, aA.w};
      const float bv[8] = {bA.x, bA.y, bA.z, bA.w, bB.x, bB.y, bB.z, bB.w};
#pragma unroll
      for (int i = 0; i < 4; ++i)
#pragma unroll
        for (int j = 0; j < 8; ++j) acc[i][j] += av[i] * bv[j];
    }
  }

#pragma unroll
  for (int i = 0; i < 4; ++i) {
    const int row = tm * 4 + i;
#pragma unroll
    for (int hh = 0; hh < 2; ++hh) {
      const int n0 = bn0 + tn * 4 + hh * 64;
      const float4 bb = *(const float4*)(bias + n0);
      float4 o;
      o.x = acc[i][hh * 4 + 0] + bb.x;
      o.y = acc[i][hh * 4 + 1] + bb.y;
      o.z = acc[i][hh * 4 + 2] + bb.z;
      o.w = acc[i][hh * 4 + 3] + bb.w;
      *(float4*)(C + (size_t)row * kV + n0) = o;
    }
  }
}

}  // namespace

extern "C" void kernel_launch(void* const* d_in, const int* in_sizes, int n_in,
                              void* d_out, int out_size, void* d_ws, size_t ws_size,
                              hipStream_t stream)
{
  const int*   seq     = (const int*)  d_in[0];
  const float* embed   = (const float*)d_in[1];
  const float* w1      = (const float*)d_in[2];
  const float* b1      = (const float*)d_in[3];
  const float* w2      = (const float*)d_in[4];
  const float* b2      = (const float*)d_in[5];
  const float* ln_g    = (const float*)d_in[6];
  const float* ln_b    = (const float*)d_in[7];
  const float* sem_w   = (const float*)d_in[8];
  const float* sem_b   = (const float*)d_in[9];
  const float* epi_w   = (const float*)d_in[10];
  const float* epi_b   = (const float*)d_in[11];
  const float* out_w   = (const float*)d_in[12];
  const float* out_b   = (const float*)d_in[13];
  const float* pos_emb = (const float*)d_in[14];
  const float* pos_w   = (const float*)d_in[15];
  const float* pos_b   = (const float*)d_in[16];
  float* out = (float*)d_out;

  // chunk size: 16384 needs 240.3 MB of ws; fall back to 8192 if tight.
  // ws_size is constant per process -> deterministic, graph-capture-safe.
  const int chunkN = (ws_size >= (size_t)240500000) ? 16384 : 8192;
  const int nch    = kTok / chunkN;

  char* p = (char*)d_ws;
  _Float16* w1th = (_Float16*)p; p += (size_t)1024 * 512 * 2;
  _Float16* w1tl = (_Float16*)p; p += (size_t)1024 * 512 * 2;
  _Float16* w2th = (_Float16*)p; p += (size_t)512 * 1024 * 2;
  _Float16* w2tl = (_Float16*)p; p += (size_t)512 * 1024 * 2;
  _Float16* wseh = (_Float16*)p; p += (size_t)512 * 512 * 2;
  _Float16* wsel = (_Float16*)p; p += (size_t)512 * 512 * 2;
  _Float16* t1h  = (_Float16*)p; p += (size_t)chunkN * 1024 * 2;
  _Float16* t1l  = (_Float16*)p; p += (size_t)chunkN * 1024 * 2;
  float*    x    = (float*)p;    p += (size_t)chunkN * kH * 4;
  float*    ks   = (float*)p;    p += (size_t)kTok * kHalf * 4;
  float*    ke   = (float*)p;    p += (size_t)kTok * kHalf * 4;
  float*    wts  = (float*)p;    p += (size_t)kL * 4;
  float*    cout_= (float*)p;    p += (size_t)kB * 512 * 4;
  _Float16* hh   = t1h;          // alias: t1 dead once x is written
  _Float16* hl   = t1l;

  pos_kernel<<<dim3((kL + 255) / 256), dim3(256), 0, stream>>>(pos_emb, pos_w, pos_b, wts);
  transpose_split<<<dim3(1024 * 512 / 256), dim3(256), 0, stream>>>(w1, w1th, w1tl, 1024, 9);
  transpose_split<<<dim3(512 * 1024 / 256), dim3(256), 0, stream>>>(w2, w2th, w2tl, 512, 10);
  transpose_split<<<dim3(256 * 512 / 256), dim3(256), 0, stream>>>(sem_w, wseh, wsel, 256, 9);
  transpose_split<<<dim3(256 * 512 / 256), dim3(256), 0, stream>>>(
      epi_w, wseh + (size_t)256 * 512, wsel + (size_t)256 * 512, 256, 9);

  for (int c = 0; c < nch; ++c) {
    const int tok0 = c * chunkN;
    hgemm<0><<<dim3(1024 / 128, chunkN / 128), dim3(256), 0, stream>>>(
        seq, embed, nullptr, nullptr, w1th, w1tl, b1, nullptr,
        nullptr, t1h, t1l, nullptr, nullptr, 512, 1024, tok0);
    hgemm<1><<<dim3(512 / 128, chunkN / 128), dim3(256), 0, stream>>>(
        seq, embed, t1h, t1l, w2th, w2tl, b2, nullptr,
        x, nullptr, nullptr, nullptr, nullptr, 1024, 512, tok0);
    ln_split<<<dim3(chunkN / 4), dim3(256), 0, stream>>>(x, ln_g, ln_b, hh, hl);
    hgemm<2><<<dim3(512 / 128, chunkN / 128), dim3(256), 0, stream>>>(
        seq, embed, hh, hl, wseh, wsel, sem_b, epi_b,
        nullptr, nullptr, nullptr, ks + (size_t)tok0 * kHalf, ke + (size_t)tok0 * kHalf,
        512, 512, tok0);
  }

  scan_chunked<<<dim3(512), dim3(256), 0, stream>>>(ks, ke, wts, cout_);
  out_gemm<<<dim3(kV / 128), dim3(256), 0, stream>>>(cout_, out_w, out_b, out);

  (void)in_sizes; (void)n_in; (void)out_size;
}